// Round 6
// baseline (307.714 us; speedup 1.0000x reference)
//
#include <hip/hip_runtime.h>
#include <hip/hip_bf16.h>

typedef __attribute__((ext_vector_type(8))) short bf16x8;
typedef __attribute__((ext_vector_type(4))) float f32x4;
typedef __attribute__((ext_vector_type(4), aligned(4))) float f32x4u;
typedef __attribute__((ext_vector_type(2), aligned(4))) float f32x2u;

__device__ __forceinline__ unsigned short f2bf(float f) {
    unsigned int u = __float_as_uint(f);
    unsigned int r = (u + 0x7fffu + ((u >> 16) & 1u)) >> 16;
    return (unsigned short)r;
}
__device__ __forceinline__ float bf2f(unsigned short u) {
    return __uint_as_float(((unsigned int)u) << 16);
}

__global__ void init_out_kernel(const float* __restrict__ x, float* __restrict__ out, int n) {
    int i = blockIdx.x * blockDim.x + threadIdx.x;
    if (i < n) out[i] = x[i];
}

// bt2[c][k]: W2^T bf16, c in [0,256), k in [0,64). W2[k][c<128] = cw1[k][c] (k<63),
// W2[k][c>=128] = cw1[64+k][c-128] (k<63); k==63 row = 0 (t folded into c0).
__global__ void prep_bt2_kernel(const float* __restrict__ cw1, unsigned short* __restrict__ bt2) {
    int idx = blockIdx.x * 256 + threadIdx.x;
    if (idx < 256 * 64) {
        int n = idx >> 6, k = idx & 63;
        float v = 0.f;
        if (k < 63) v = (n < 128) ? cw1[k * 128 + n] : cw1[(64 + k) * 128 + (n - 128)];
        bt2[n * 64 + k] = f2bf(v);
    }
}

// bt_M[col][p] = (ew2 @ cw1[128:160])^T bf16 [128][32];
// c0[j] = cb1[j] + eb2@cw1[128:160] + t*(cw1[63]+cw1[127])
__global__ void prep_consts_kernel(const float* __restrict__ ew2, const float* __restrict__ eb2,
                                   const float* __restrict__ cw1, const float* __restrict__ cb1,
                                   const int* __restrict__ tptr,
                                   unsigned short* __restrict__ bt_M, float* __restrict__ c0) {
    int j = threadIdx.x;  // 0..127, one block
    float t = (float)tptr[0];
    float cacc = cb1[j] + t * (cw1[63 * 128 + j] + cw1[127 * 128 + j]);
    float m[32];
    #pragma unroll
    for (int p = 0; p < 32; ++p) m[p] = 0.f;
    for (int i = 0; i < 32; ++i) {
        float w = cw1[(128 + i) * 128 + j];
        cacc = fmaf(eb2[i], w, cacc);
        #pragma unroll
        for (int p = 0; p < 32; ++p) m[p] = fmaf(ew2[p * 32 + i], w, m[p]);
    }
    c0[j] = cacc;
    #pragma unroll
    for (int p = 0; p < 32; ++p) bt_M[j * 32 + p] = f2bf(m[p]);
}

__device__ __forceinline__ bf16x8 load8_bf(const float* p) {
    f32x4u a = *(const f32x4u*)p;
    f32x4u b = *(const f32x4u*)(p + 4);
    bf16x8 r;
    r[0] = f2bf(a[0]); r[1] = f2bf(a[1]); r[2] = f2bf(a[2]); r[3] = f2bf(a[3]);
    r[4] = f2bf(b[0]); r[5] = f2bf(b[1]); r[6] = f2bf(b[2]); r[7] = f2bf(b[3]);
    return r;
}
__device__ __forceinline__ bf16x8 load7z_bf(const float* p) {
    f32x4u a = *(const f32x4u*)p;
    f32x2u b = *(const f32x2u*)(p + 4);
    float c = p[6];
    bf16x8 r;
    r[0] = f2bf(a[0]); r[1] = f2bf(a[1]); r[2] = f2bf(a[2]); r[3] = f2bf(a[3]);
    r[4] = f2bf(b[0]); r[5] = f2bf(b[1]); r[6] = f2bf(c);  r[7] = 0;
    return r;
}

// UV[node][256] bf16: cols 0..127 = U = cond@Wtop, cols 128..255 = V = cond@Wmid.
// A = weights (M=16 uv-cols per tile), B = nodes (N=16) -> D col = node, and each
// lane's 4 acc regs are 4 CONSECUTIVE uv-cols of ONE node -> 8B packed stores.
__global__ __launch_bounds__(256) void prep_uv_kernel(
    const float* __restrict__ cond, const unsigned short* __restrict__ bt2,
    unsigned short* __restrict__ UV, int BN)
{
    const int tid = threadIdx.x, lane = tid & 63, wid = tid >> 6;
    const int fr = lane & 15, kq = lane >> 4;
    int node = blockIdx.x * 64 + wid * 16 + fr;
    if (node >= BN) node = BN - 1;

    // B-frags: B[k][col=fr] = cond[node][k]
    const float* cp = cond + (long)node * 63;
    bf16x8 b0 = load8_bf(cp + 8 * kq);
    bf16x8 b1 = (kq < 3) ? load8_bf(cp + 32 + 8 * kq) : load7z_bf(cp + 56);

    char* UVb = (char*)UV;
    const unsigned off = ((unsigned)node * 256u + (unsigned)(kq * 4)) * 2u;

    #pragma unroll
    for (int n = 0; n < 16; ++n) {
        // A-frag: A[row=fr][k] = W2[k][uvcol = n*16+fr] = bt2[(n*16+fr)*64 + k]
        bf16x8 a0 = *reinterpret_cast<const bf16x8*>(&bt2[(n * 16 + fr) * 64 + 8 * kq]);
        bf16x8 a1 = *reinterpret_cast<const bf16x8*>(&bt2[(n * 16 + fr) * 64 + 32 + 8 * kq]);
        f32x4 acc = (f32x4){0.f, 0.f, 0.f, 0.f};
        acc = __builtin_amdgcn_mfma_f32_16x16x32_bf16(a0, b0, acc, 0, 0, 0);
        acc = __builtin_amdgcn_mfma_f32_16x16x32_bf16(a1, b1, acc, 0, 0, 0);
        // D[row=kq*4+r][col=fr] -> UV[node][n*16 + kq*4 + r], r=0..3 consecutive
        uint2 pk;
        pk.x = (unsigned)f2bf(acc[0]) | ((unsigned)f2bf(acc[1]) << 16);
        pk.y = (unsigned)f2bf(acc[2]) | ((unsigned)f2bf(acc[3]) << 16);
        *reinterpret_cast<uint2*>(UVb + off + n * 32) = pk;
    }
}

__global__ __launch_bounds__(256, 4) void edge_kernel(
    const float* __restrict__ x, const float* __restrict__ edge_dist,
    const float* __restrict__ ew1, const float* __restrict__ eb1,
    const unsigned short* __restrict__ bt_M, const float* __restrict__ c0f,
    const float* __restrict__ cw2, const unsigned short* __restrict__ UV,
    const int* __restrict__ edge_index, float* __restrict__ out, int E)
{
    __shared__ __align__(16) unsigned short s_lds[128][40];  // stride 80B = 16B-aligned
    __shared__ int srcl[128];
    __shared__ int dstl[128];
    __shared__ float cw_lds[128];

    const int tid = threadIdx.x, lane = tid & 63, wid = tid >> 6;
    const int fr = lane & 15, kq = lane >> 4;
    const int e0 = blockIdx.x * 128;

    // ---- phase A (balanced): every thread loads 1 index + computes 16 silu ----
    {
        int ei = e0 + (tid & 127); if (ei >= E) ei = E - 1;
        if (tid < 128) srcl[tid] = edge_index[ei];
        else           dstl[tid - 128] = edge_index[E + ei];

        int eh = tid >> 1;                  // edge row 0..127
        int e  = e0 + eh; if (e >= E) e = E - 1;
        int j0 = (tid & 1) * 16;
        float dist = edge_dist[e];
        #pragma unroll
        for (int i = 0; i < 8; ++i) {
            float v0 = fmaf(dist, ew1[j0 + 2 * i],     eb1[j0 + 2 * i]);
            float v1 = fmaf(dist, ew1[j0 + 2 * i + 1], eb1[j0 + 2 * i + 1]);
            float s0 = v0 / (1.f + __expf(-v0));
            float s1 = v1 / (1.f + __expf(-v1));
            unsigned pk = (unsigned)f2bf(s0) | ((unsigned)f2bf(s1) << 16);
            *reinterpret_cast<unsigned*>(&s_lds[eh][j0 + 2 * i]) = pk;
        }
    }
    __syncthreads();

    // A-frags for s.M: row(edge)=fr, k=8kq+j
    bf16x8 a[2];
    #pragma unroll
    for (int m = 0; m < 2; ++m)
        a[m] = *reinterpret_cast<const bf16x8*>(&s_lds[wid * 32 + m * 16 + fr][8 * kq]);

    // byte offsets into UV for the 8 edges this lane owns (D row = kq*4+r)
    unsigned bu[2][4], bv[2][4];
    #pragma unroll
    for (int m = 0; m < 2; ++m)
        #pragma unroll
        for (int r = 0; r < 4; ++r) {
            int row = wid * 32 + m * 16 + kq * 4 + r;
            bu[m][r] = ((unsigned)srcl[row] * 256u + (unsigned)fr) * 2u;
            bv[m][r] = ((unsigned)dstl[row] * 256u + 128u + (unsigned)fr) * 2u;
        }

    const char* UVb = (const char*)UV;
    float psum[2][4] = {{0.f,0.f,0.f,0.f},{0.f,0.f,0.f,0.f}};

    #pragma unroll 1
    for (int nh = 0; nh < 2; ++nh) {
        f32x4 acc[2][4];
        #pragma unroll
        for (int n = 0; n < 4; ++n) {
            float c = c0f[(nh * 4 + n) * 16 + fr];
            acc[0][n] = (f32x4){c, c, c, c};
            acc[1][n] = (f32x4){c, c, c, c};
        }
        #pragma unroll
        for (int n = 0; n < 4; ++n) {
            int col = (nh * 4 + n) * 16 + fr;
            bf16x8 b = *reinterpret_cast<const bf16x8*>(&bt_M[col * 32 + 8 * kq]);
            acc[0][n] = __builtin_amdgcn_mfma_f32_16x16x32_bf16(a[0], b, acc[0][n], 0, 0, 0);
            acc[1][n] = __builtin_amdgcn_mfma_f32_16x16x32_bf16(a[1], b, acc[1][n], 0, 0, 0);
        }
        #pragma unroll
        for (int n = 0; n < 4; ++n) {
            float w2 = cw2[(nh * 4 + n) * 16 + fr];
            const int cb = (nh * 4 + n) * 32;   // compile-time byte offset per n
            #pragma unroll
            for (int m = 0; m < 2; ++m)
                #pragma unroll
                for (int r = 0; r < 4; ++r) {
                    unsigned short uu = *reinterpret_cast<const unsigned short*>(UVb + bu[m][r] + cb);
                    unsigned short vv = *reinterpret_cast<const unsigned short*>(UVb + bv[m][r] + cb);
                    float h = acc[m][n][r] + bf2f(uu) + bf2f(vv);
                    float sil = h / (1.f + __expf(-h));
                    psum[m][r] = fmaf(sil, w2, psum[m][r]);
                }
        }
    }

    // reduce over the 16 fr lanes (cols ≡ fr mod 16)
    #pragma unroll
    for (int off = 1; off < 16; off <<= 1)
        #pragma unroll
        for (int m = 0; m < 2; ++m)
            #pragma unroll
            for (int r = 0; r < 4; ++r)
                psum[m][r] += __shfl_xor(psum[m][r], off, 64);
    if (fr == 0) {
        #pragma unroll
        for (int m = 0; m < 2; ++m) {
            int row0 = wid * 32 + m * 16 + kq * 4;
            #pragma unroll
            for (int r = 0; r < 4; ++r) cw_lds[row0 + r] = psum[m][r];
        }
    }
    __syncthreads();

    if (tid < 128) {
        int e = e0 + tid;
        if (e < E) {
            float coord_w = cw_lds[tid];
            int src = srcl[tid];
            int dst = dstl[tid];
            float dx = x[src * 3 + 0] - x[dst * 3 + 0];
            float dy = x[src * 3 + 1] - x[dst * 3 + 1];
            float dz = x[src * 3 + 2] - x[dst * 3 + 2];
            float len = sqrtf(fmaf(dx, dx, fmaf(dy, dy, dz * dz)));
            len = fmaxf(len, 1e-8f);
            float sc = coord_w / len;
            atomicAdd(&out[dst * 3 + 0], sc * dx);
            atomicAdd(&out[dst * 3 + 1], sc * dy);
            atomicAdd(&out[dst * 3 + 2], sc * dz);
        }
    }
}

extern "C" void kernel_launch(void* const* d_in, const int* in_sizes, int n_in,
                              void* d_out, int out_size, void* d_ws, size_t ws_size,
                              hipStream_t stream) {
    const float* x         = (const float*)d_in[0];
    const float* cond      = (const float*)d_in[1];
    const float* edge_dist = (const float*)d_in[2];
    const float* ew1       = (const float*)d_in[3];
    const float* eb1       = (const float*)d_in[4];
    const float* ew2       = (const float*)d_in[5];
    const float* eb2       = (const float*)d_in[6];
    // d_in[7..10] = node_mlp weights: dead code (h_out discarded by reference)
    const float* cw1       = (const float*)d_in[11];
    const float* cb1       = (const float*)d_in[12];
    const float* cw2       = (const float*)d_in[13];
    const int*   edge_index= (const int*)d_in[14];
    const int*   tptr      = (const int*)d_in[15];
    float* out = (float*)d_out;

    const int E  = in_sizes[2];        // 800000
    const int BN = in_sizes[1] / 63;   // 50000
    const int n_out = out_size;        // 150000

    // workspace layout
    char* ws = (char*)d_ws;
    unsigned short* bt_M = (unsigned short*)(ws);            // 8 KB
    float*          c0   = (float*)(ws + 8192);              // 512 B
    unsigned short* bt2  = (unsigned short*)(ws + 16384);    // 32 KB
    unsigned short* UV   = (unsigned short*)(ws + 65536);    // BN*256*2 = 25.6 MB

    init_out_kernel<<<(n_out + 255) / 256, 256, 0, stream>>>(x, out, n_out);
    prep_bt2_kernel<<<64, 256, 0, stream>>>(cw1, bt2);
    prep_consts_kernel<<<1, 128, 0, stream>>>(ew2, eb2, cw1, cb1, tptr, bt_M, c0);
    prep_uv_kernel<<<(BN + 63) / 64, 256, 0, stream>>>(cond, bt2, UV, BN);

    int blocks = (E + 127) / 128;
    edge_kernel<<<blocks, 256, 0, stream>>>(x, edge_dist, ew1, eb1,
                                            bt_M, c0, cw2, UV,
                                            edge_index, out, E);
}

// Round 7
// 286.675 us; speedup vs baseline: 1.0734x; 1.0734x over previous
//
#include <hip/hip_runtime.h>
#include <hip/hip_bf16.h>

typedef __attribute__((ext_vector_type(8))) short bf16x8;
typedef __attribute__((ext_vector_type(4))) float f32x4;
typedef __attribute__((ext_vector_type(4), aligned(4))) float f32x4u;
typedef __attribute__((ext_vector_type(2), aligned(4))) float f32x2u;

__device__ __forceinline__ unsigned short f2bf(float f) {
    unsigned int u = __float_as_uint(f);
    unsigned int r = (u + 0x7fffu + ((u >> 16) & 1u)) >> 16;
    return (unsigned short)r;
}
__device__ __forceinline__ float bflo(unsigned int u) { return __uint_as_float(u << 16); }
__device__ __forceinline__ float bfhi(unsigned int u) { return __uint_as_float(u & 0xffff0000u); }

__global__ void init_out_kernel(const float* __restrict__ x, float* __restrict__ out, int n) {
    int i = blockIdx.x * blockDim.x + threadIdx.x;
    if (i < n) out[i] = x[i];
}

// bt2[c][k]: W2^T bf16, c in [0,256), k in [0,64). W2[k][c<128] = cw1[k][c] (k<63),
// W2[k][c>=128] = cw1[64+k][c-128] (k<63); k==63 row = 0 (t folded into c0).
__global__ void prep_bt2_kernel(const float* __restrict__ cw1, unsigned short* __restrict__ bt2) {
    int idx = blockIdx.x * 256 + threadIdx.x;
    if (idx < 256 * 64) {
        int n = idx >> 6, k = idx & 63;
        float v = 0.f;
        if (k < 63) v = (n < 128) ? cw1[k * 128 + n] : cw1[(64 + k) * 128 + (n - 128)];
        bt2[n * 64 + k] = f2bf(v);
    }
}

// bt_M[col][p] = (ew2 @ cw1[128:160])^T bf16 [128][32];
// c0[j] = cb1[j] + eb2@cw1[128:160] + t*(cw1[63]+cw1[127])
__global__ void prep_consts_kernel(const float* __restrict__ ew2, const float* __restrict__ eb2,
                                   const float* __restrict__ cw1, const float* __restrict__ cb1,
                                   const int* __restrict__ tptr,
                                   unsigned short* __restrict__ bt_M, float* __restrict__ c0) {
    int j = threadIdx.x;  // 0..127, one block
    float t = (float)tptr[0];
    float cacc = cb1[j] + t * (cw1[63 * 128 + j] + cw1[127 * 128 + j]);
    float m[32];
    #pragma unroll
    for (int p = 0; p < 32; ++p) m[p] = 0.f;
    for (int i = 0; i < 32; ++i) {
        float w = cw1[(128 + i) * 128 + j];
        cacc = fmaf(eb2[i], w, cacc);
        #pragma unroll
        for (int p = 0; p < 32; ++p) m[p] = fmaf(ew2[p * 32 + i], w, m[p]);
    }
    c0[j] = cacc;
    #pragma unroll
    for (int p = 0; p < 32; ++p) bt_M[j * 32 + p] = f2bf(m[p]);
}

__device__ __forceinline__ bf16x8 load8_bf(const float* p) {
    f32x4u a = *(const f32x4u*)p;
    f32x4u b = *(const f32x4u*)(p + 4);
    bf16x8 r;
    r[0] = f2bf(a[0]); r[1] = f2bf(a[1]); r[2] = f2bf(a[2]); r[3] = f2bf(a[3]);
    r[4] = f2bf(b[0]); r[5] = f2bf(b[1]); r[6] = f2bf(b[2]); r[7] = f2bf(b[3]);
    return r;
}
__device__ __forceinline__ bf16x8 load7z_bf(const float* p) {
    f32x4u a = *(const f32x4u*)p;
    f32x2u b = *(const f32x2u*)(p + 4);
    float c = p[6];
    bf16x8 r;
    r[0] = f2bf(a[0]); r[1] = f2bf(a[1]); r[2] = f2bf(a[2]); r[3] = f2bf(a[3]);
    r[4] = f2bf(b[0]); r[5] = f2bf(b[1]); r[6] = f2bf(c);  r[7] = 0;
    return r;
}

// UV[node][256] bf16: cols 0..127 = U = cond@Wtop, cols 128..255 = V = cond@Wmid.
// A = weights, B = nodes -> D col = node; lane's 4 acc regs = 4 consecutive uv-cols.
__global__ __launch_bounds__(256) void prep_uv_kernel(
    const float* __restrict__ cond, const unsigned short* __restrict__ bt2,
    unsigned short* __restrict__ UV, int BN)
{
    const int tid = threadIdx.x, lane = tid & 63, wid = tid >> 6;
    const int fr = lane & 15, kq = lane >> 4;
    int node = blockIdx.x * 64 + wid * 16 + fr;
    if (node >= BN) node = BN - 1;

    const float* cp = cond + (long)node * 63;
    bf16x8 b0 = load8_bf(cp + 8 * kq);
    bf16x8 b1 = (kq < 3) ? load8_bf(cp + 32 + 8 * kq) : load7z_bf(cp + 56);

    char* UVb = (char*)UV;
    const unsigned off = ((unsigned)node * 256u + (unsigned)(kq * 4)) * 2u;

    #pragma unroll
    for (int n = 0; n < 16; ++n) {
        bf16x8 a0 = *reinterpret_cast<const bf16x8*>(&bt2[(n * 16 + fr) * 64 + 8 * kq]);
        bf16x8 a1 = *reinterpret_cast<const bf16x8*>(&bt2[(n * 16 + fr) * 64 + 32 + 8 * kq]);
        f32x4 acc = (f32x4){0.f, 0.f, 0.f, 0.f};
        acc = __builtin_amdgcn_mfma_f32_16x16x32_bf16(a0, b0, acc, 0, 0, 0);
        acc = __builtin_amdgcn_mfma_f32_16x16x32_bf16(a1, b1, acc, 0, 0, 0);
        uint2 pk;
        pk.x = (unsigned)f2bf(acc[0]) | ((unsigned)f2bf(acc[1]) << 16);
        pk.y = (unsigned)f2bf(acc[2]) | ((unsigned)f2bf(acc[3]) << 16);
        *reinterpret_cast<uint2*>(UVb + off + n * 32) = pk;
    }
}

__global__ __launch_bounds__(256, 4) void edge_kernel(
    const float* __restrict__ x, const float* __restrict__ edge_dist,
    const float* __restrict__ ew1, const float* __restrict__ eb1,
    const unsigned short* __restrict__ bt_M, const float* __restrict__ c0f,
    const float* __restrict__ cw2, const unsigned short* __restrict__ UV,
    const int* __restrict__ edge_index, float* __restrict__ out, int E)
{
    __shared__ __align__(16) unsigned short s_lds[128][40];  // stride 80B
    __shared__ int srcl[128];
    __shared__ int dstl[128];
    __shared__ float cw_lds[128];

    const int tid = threadIdx.x, lane = tid & 63, wid = tid >> 6;
    const int fr = lane & 15, kq = lane >> 4;
    const int e0 = blockIdx.x * 128;

    // ---- phase A (round-5 style): waves 0-1 silu with WAVE-UNIFORM ew1 rows
    //      (-> s_load broadcasts); waves 2-3 load edge indices ----
    if (tid < 128) {
        int e = e0 + tid; if (e >= E) e = E - 1;
        float dist = edge_dist[e];
        #pragma unroll
        for (int i = 0; i < 16; ++i) {
            float v0 = fmaf(dist, ew1[2 * i],     eb1[2 * i]);
            float v1 = fmaf(dist, ew1[2 * i + 1], eb1[2 * i + 1]);
            float s0 = v0 / (1.f + __expf(-v0));
            float s1 = v1 / (1.f + __expf(-v1));
            unsigned pk = (unsigned)f2bf(s0) | ((unsigned)f2bf(s1) << 16);
            *reinterpret_cast<unsigned*>(&s_lds[tid][2 * i]) = pk;
        }
    } else {
        int r = tid - 128;
        int e = e0 + r; if (e >= E) e = E - 1;
        srcl[r] = edge_index[e];
        dstl[r] = edge_index[E + e];
    }
    __syncthreads();

    // B-frags (edges as MFMA columns): lane(col=fr,kq) holds s[edge][k=8kq+j]
    bf16x8 sb[2];
    #pragma unroll
    for (int m = 0; m < 2; ++m)
        sb[m] = *reinterpret_cast<const bf16x8*>(&s_lds[wid * 32 + m * 16 + fr][8 * kq]);

    // per-lane UV byte bases for its 2 edges (cols kq*4.. handled via +n*32 imm)
    unsigned bu[2], bv[2];
    #pragma unroll
    for (int m = 0; m < 2; ++m) {
        int row = wid * 32 + m * 16 + fr;
        bu[m] = (unsigned)srcl[row] * 512u + (unsigned)(kq * 8);
        bv[m] = (unsigned)dstl[row] * 512u + 256u + (unsigned)(kq * 8);
    }

    const char* UVb = (const char*)UV;
    float psum[2] = {0.f, 0.f};

    #pragma unroll 1
    for (int nh = 0; nh < 2; ++nh) {
        // acc[m][n][r] = H[col=(nh*4+n)*16+kq*4+r][edge m] ; init with c0 rows
        f32x4 acc[2][4];
        #pragma unroll
        for (int n = 0; n < 4; ++n) {
            f32x4u c = *reinterpret_cast<const f32x4u*>(c0f + (nh * 4 + n) * 16 + kq * 4);
            acc[0][n] = (f32x4){c[0], c[1], c[2], c[3]};
            acc[1][n] = acc[0][n];
        }
        #pragma unroll
        for (int n = 0; n < 4; ++n) {
            // A-frag: row=fr -> weight col (nh*4+n)*16+fr, k contiguous
            bf16x8 aw = *reinterpret_cast<const bf16x8*>(&bt_M[((nh * 4 + n) * 16 + fr) * 32 + 8 * kq]);
            acc[0][n] = __builtin_amdgcn_mfma_f32_16x16x32_bf16(aw, sb[0], acc[0][n], 0, 0, 0);
            acc[1][n] = __builtin_amdgcn_mfma_f32_16x16x32_bf16(aw, sb[1], acc[1][n], 0, 0, 0);
        }
        #pragma unroll
        for (int n = 0; n < 4; ++n) {
            f32x4u w2 = *reinterpret_cast<const f32x4u*>(cw2 + (nh * 4 + n) * 16 + kq * 4);
            const int cb = (nh * 4 + n) * 32;   // compile-time byte offset
            #pragma unroll
            for (int m = 0; m < 2; ++m) {
                uint2 uu = *reinterpret_cast<const uint2*>(UVb + bu[m] + cb);
                uint2 vv = *reinterpret_cast<const uint2*>(UVb + bv[m] + cb);
                float uf[4] = {bflo(uu.x), bfhi(uu.x), bflo(uu.y), bfhi(uu.y)};
                float vf[4] = {bflo(vv.x), bfhi(vv.x), bflo(vv.y), bfhi(vv.y)};
                #pragma unroll
                for (int r = 0; r < 4; ++r) {
                    float h = acc[m][n][r] + uf[r] + vf[r];
                    float sil = h / (1.f + __expf(-h));
                    psum[m] = fmaf(sil, w2[r], psum[m]);
                }
            }
        }
    }

    // reduce across the 4 kq groups (lanes fr, fr+16, fr+32, fr+48)
    #pragma unroll
    for (int m = 0; m < 2; ++m) {
        psum[m] += __shfl_xor(psum[m], 16, 64);
        psum[m] += __shfl_xor(psum[m], 32, 64);
    }
    if (kq == 0) {
        #pragma unroll
        for (int m = 0; m < 2; ++m)
            cw_lds[wid * 32 + m * 16 + fr] = psum[m];
    }
    __syncthreads();

    if (tid < 128) {
        int e = e0 + tid;
        if (e < E) {
            float coord_w = cw_lds[tid];
            int src = srcl[tid];
            int dst = dstl[tid];
            float dx = x[src * 3 + 0] - x[dst * 3 + 0];
            float dy = x[src * 3 + 1] - x[dst * 3 + 1];
            float dz = x[src * 3 + 2] - x[dst * 3 + 2];
            float len = sqrtf(fmaf(dx, dx, fmaf(dy, dy, dz * dz)));
            len = fmaxf(len, 1e-8f);
            float sc = coord_w / len;
            atomicAdd(&out[dst * 3 + 0], sc * dx);
            atomicAdd(&out[dst * 3 + 1], sc * dy);
            atomicAdd(&out[dst * 3 + 2], sc * dz);
        }
    }
}

extern "C" void kernel_launch(void* const* d_in, const int* in_sizes, int n_in,
                              void* d_out, int out_size, void* d_ws, size_t ws_size,
                              hipStream_t stream) {
    const float* x         = (const float*)d_in[0];
    const float* cond      = (const float*)d_in[1];
    const float* edge_dist = (const float*)d_in[2];
    const float* ew1       = (const float*)d_in[3];
    const float* eb1       = (const float*)d_in[4];
    const float* ew2       = (const float*)d_in[5];
    const float* eb2       = (const float*)d_in[6];
    // d_in[7..10] = node_mlp weights: dead code (h_out discarded by reference)
    const float* cw1       = (const float*)d_in[11];
    const float* cb1       = (const float*)d_in[12];
    const float* cw2       = (const float*)d_in[13];
    const int*   edge_index= (const int*)d_in[14];
    const int*   tptr      = (const int*)d_in[15];
    float* out = (float*)d_out;

    const int E  = in_sizes[2];        // 800000
    const int BN = in_sizes[1] / 63;   // 50000
    const int n_out = out_size;        // 150000

    char* ws = (char*)d_ws;
    unsigned short* bt_M = (unsigned short*)(ws);            // 8 KB
    float*          c0   = (float*)(ws + 8192);              // 512 B
    unsigned short* bt2  = (unsigned short*)(ws + 16384);    // 32 KB
    unsigned short* UV   = (unsigned short*)(ws + 65536);    // BN*256*2 = 25.6 MB

    init_out_kernel<<<(n_out + 255) / 256, 256, 0, stream>>>(x, out, n_out);
    prep_bt2_kernel<<<64, 256, 0, stream>>>(cw1, bt2);
    prep_consts_kernel<<<1, 128, 0, stream>>>(ew2, eb2, cw1, cb1, tptr, bt_M, c0);
    prep_uv_kernel<<<(BN + 63) / 64, 256, 0, stream>>>(cond, bt2, UV, BN);

    int blocks = (E + 127) / 128;
    edge_kernel<<<blocks, 256, 0, stream>>>(x, edge_dist, ew1, eb1,
                                            bt_M, c0, cw2, UV,
                                            edge_index, out, E);
}